// Round 1
// baseline (1294.640 us; speedup 1.0000x reference)
//
#include <hip/hip_runtime.h>
#include <math.h>

#define H 8
#define D 32
// MESSAGE_DIM = H*D = 256

// Sign-split float atomic max: works for cells initialized to -inf.
// Non-negative values: int-ordered max. Negative values: uint-ordered min.
__device__ __forceinline__ void atomicMaxFloat(float* addr, float val) {
    if (val >= 0.0f) {
        atomicMax((int*)addr, __float_as_int(val));
    } else {
        atomicMin((unsigned int*)addr, __float_as_uint(val));
    }
}

__global__ void aew_init_kernel(float* __restrict__ mx, float* __restrict__ s, int n) {
    int i = blockIdx.x * blockDim.x + threadIdx.x;
    if (i < n) {
        mx[i] = -INFINITY;
        s[i]  = 0.0f;
    }
}

// One thread per (edge, head). gid = e*8 + h.
__global__ __launch_bounds__(256) void aew_score_kernel(
    const int*   __restrict__ target,
    const float* __restrict__ message,
    const float* __restrict__ x_e,
    const float* __restrict__ weight,
    float*       __restrict__ alpha,
    float*       __restrict__ mx,
    int EH)
{
    // Stage weight (8 x 64) in LDS with a per-head rotation of 4 elements so
    // that for a fixed k, the 8 head-streams land in 8 distinct banks.
    __shared__ float wsm[H * 2 * D];
    for (int i = threadIdx.x; i < H * 2 * D; i += blockDim.x) {
        int hh = i >> 6;
        int kk = i & 63;
        wsm[hh * 64 + ((kk + hh * 4) & 63)] = weight[i];
    }
    __syncthreads();

    int gid = blockIdx.x * blockDim.x + threadIdx.x;
    if (gid >= EH) return;
    int e = gid >> 3;
    int h = gid & 7;
    int t = target[e];

    const float4* m4 = (const float4*)(message + (size_t)e * 256 + h * 32);
    const float4* x4 = (const float4*)(x_e     + (size_t)t * 256 + h * 32);

    float acc = 0.0f;
    #pragma unroll
    for (int j = 0; j < 8; ++j) {
        float4 mv = m4[j];
        float4 xv = x4[j];
        // w1[k] = weight[h][k], w2[k] = weight[h][32+k], stored rotated by h*4
        int k0 = j * 4;
        float w10 = wsm[h * 64 + ((k0 + 0 + h * 4) & 63)];
        float w11 = wsm[h * 64 + ((k0 + 1 + h * 4) & 63)];
        float w12 = wsm[h * 64 + ((k0 + 2 + h * 4) & 63)];
        float w13 = wsm[h * 64 + ((k0 + 3 + h * 4) & 63)];
        float w20 = wsm[h * 64 + ((k0 + 32 + 0 + h * 4) & 63)];
        float w21 = wsm[h * 64 + ((k0 + 32 + 1 + h * 4) & 63)];
        float w22 = wsm[h * 64 + ((k0 + 32 + 2 + h * 4) & 63)];
        float w23 = wsm[h * 64 + ((k0 + 32 + 3 + h * 4) & 63)];
        acc += mv.x * w10 + mv.y * w11 + mv.z * w12 + mv.w * w13;
        acc += xv.x * w20 + xv.y * w21 + xv.z * w22 + xv.w * w23;
    }

    float a = (acc >= 0.0f) ? acc : 0.1f * acc;  // LeakyReLU(0.1)
    alpha[gid] = a;
    atomicMaxFloat(&mx[t * H + h], a);
}

// One thread per (edge, head): ex = exp(alpha - mx[target]); accumulate sums.
__global__ __launch_bounds__(256) void aew_expsum_kernel(
    const int*   __restrict__ target,
    float*       __restrict__ alpha,   // in: score, out: ex
    const float* __restrict__ mx,
    float*       __restrict__ s,
    int EH)
{
    int gid = blockIdx.x * blockDim.x + threadIdx.x;
    if (gid >= EH) return;
    int e = gid >> 3;
    int h = gid & 7;
    int t = target[e];
    float ex = expf(alpha[gid] - mx[t * H + h]);
    alpha[gid] = ex;
    atomicAdd(&s[t * H + h], ex);
}

// Flat float4 elementwise: out = message * (ex / max(s[target], 1e-16)).
// i4 indexes float4 elements; 64 float4 per edge row; 8 per head.
__global__ __launch_bounds__(256) void aew_output_kernel(
    const int*   __restrict__ target,
    const float* __restrict__ message,
    const float* __restrict__ ex,
    const float* __restrict__ s,
    float*       __restrict__ out,
    int n4)
{
    int i4 = blockIdx.x * blockDim.x + threadIdx.x;
    if (i4 >= n4) return;
    int e = i4 >> 6;
    int h = (i4 & 63) >> 3;
    int t = target[e];
    float sc = ex[e * H + h] / fmaxf(s[t * H + h], 1e-16f);
    float4 mv = ((const float4*)message)[i4];
    float4 o;
    o.x = mv.x * sc;
    o.y = mv.y * sc;
    o.z = mv.z * sc;
    o.w = mv.w * sc;
    ((float4*)out)[i4] = o;
}

extern "C" void kernel_launch(void* const* d_in, const int* in_sizes, int n_in,
                              void* d_out, int out_size, void* d_ws, size_t ws_size,
                              hipStream_t stream) {
    // inputs: source(E), target(E), message(E*256), x_e(N*256), weight(8*64)
    const int*   target  = (const int*)d_in[1];
    const float* message = (const float*)d_in[2];
    const float* x_e     = (const float*)d_in[3];
    const float* weight  = (const float*)d_in[4];
    float* out = (float*)d_out;

    const int E = in_sizes[1];
    const int N = in_sizes[3] / 256;
    const int EH = E * H;
    const int NH = N * H;

    // ws layout: alpha/ex (E*H f32) | mx (N*H f32) | s (N*H f32)  ~57.6 MB
    float* alpha = (float*)d_ws;
    float* mx    = alpha + (size_t)EH;
    float* s     = mx + (size_t)NH;

    aew_init_kernel<<<(NH + 255) / 256, 256, 0, stream>>>(mx, s, NH);
    aew_score_kernel<<<(EH + 255) / 256, 256, 0, stream>>>(target, message, x_e, weight, alpha, mx, EH);
    aew_expsum_kernel<<<(EH + 255) / 256, 256, 0, stream>>>(target, alpha, mx, s, EH);
    const int n4 = E * 64;  // E*256/4 float4 elements
    aew_output_kernel<<<(n4 + 255) / 256, 256, 0, stream>>>(target, message, alpha, s, out, n4);
}